// Round 1
// baseline (35.357 us; speedup 1.0000x reference)
//
#include <hip/hip_runtime.h>

// NumberPlateDetector: X (128,64,64,9,5) f32 -> boxes (N,5), N = 4,718,592
// out = concat flat: xyxy (N,4) f32, keep (N,) as 0/1 f32
// Memory-bound elementwise. Each thread handles 4 boxes = 20 contiguous
// floats = 5 float4 loads; writes 4 float4 (xyxy) + 1 float4 (keep).

__global__ __launch_bounds__(256) void plate_kernel(
    const float* __restrict__ X,
    const float* __restrict__ thr_p,
    float* __restrict__ out_xyxy,
    float* __restrict__ out_keep,
    int nquads)
{
    int t = blockIdx.x * blockDim.x + threadIdx.x;
    if (t >= nquads) return;

    const float thr = thr_p[0];

    // 4 boxes = 20 floats = 5 float4, base offset t*80 bytes (16B-aligned)
    const float4* __restrict__ src = reinterpret_cast<const float4*>(X) + (size_t)t * 5;
    float f[20];
    #pragma unroll
    for (int i = 0; i < 5; ++i) {
        float4 v = src[i];
        f[i * 4 + 0] = v.x;
        f[i * 4 + 1] = v.y;
        f[i * 4 + 2] = v.z;
        f[i * 4 + 3] = v.w;
    }

    float4 res[4];
    float  kf[4];
    #pragma unroll
    for (int b = 0; b < 4; ++b) {
        float x = f[b * 5 + 0];
        float y = f[b * 5 + 1];
        float w = f[b * 5 + 2];
        float h = f[b * 5 + 3];
        float s = f[b * 5 + 4];
        bool keep = s > thr;
        float hw = w * 0.5f;
        float hh = h * 0.5f;
        float4 r;
        r.x = keep ? (x - hw) : 0.0f;
        r.y = keep ? (y - hh) : 0.0f;
        r.z = keep ? (x + hw) : 0.0f;
        r.w = keep ? (y + hh) : 0.0f;
        res[b] = r;
        kf[b]  = keep ? 1.0f : 0.0f;
    }

    float4* __restrict__ dst = reinterpret_cast<float4*>(out_xyxy) + (size_t)t * 4;
    #pragma unroll
    for (int b = 0; b < 4; ++b) dst[b] = res[b];

    reinterpret_cast<float4*>(out_keep)[t] = make_float4(kf[0], kf[1], kf[2], kf[3]);
}

extern "C" void kernel_launch(void* const* d_in, const int* in_sizes, int n_in,
                              void* d_out, int out_size, void* d_ws, size_t ws_size,
                              hipStream_t stream)
{
    const float* X   = (const float*)d_in[0];
    const float* thr = (const float*)d_in[1];

    const long long n_boxes = (long long)in_sizes[0] / 5;   // 4,718,592
    const int nquads = (int)(n_boxes / 4);                  // 1,179,648 (N%4==0)

    float* out_xyxy = (float*)d_out;                        // N*4 floats
    float* out_keep = (float*)d_out + n_boxes * 4;          // N floats

    const int block = 256;
    const int grid  = (nquads + block - 1) / block;         // 4608 blocks

    plate_kernel<<<grid, block, 0, stream>>>(X, thr, out_xyxy, out_keep, nquads);
}

// Round 2
// 32.752 us; speedup vs baseline: 1.0795x; 1.0795x over previous
//
#include <hip/hip_runtime.h>

// NumberPlateDetector: X (128,64,64,9,5) f32 -> boxes (N,5), N = 4,718,592
// out = concat flat: xyxy (N,4) f32, keep (N,) as 0/1 f32
//
// Memory-bound. LDS-staged transpose so every global load/store is
// lane-adjacent (fully coalesced):
//   - block = 256 threads, tile = 1024 boxes = 5120 floats = 1280 float4
//   - load: 5 coalesced float4 per thread -> LDS (20 KB)
//   - compute: thread j handles boxes {j, 256+j, 512+j, 768+j}; LDS reads
//     at float-stride 5 (gcd(5,32)=1 -> only free 2-way lane aliasing)
//   - store: 1 coalesced float4 (xyxy) + 1 coalesced scalar (keep) per box,
//     non-temporal (outputs never re-read -> keep X resident in L3)

using f4 = __attribute__((ext_vector_type(4))) float;

__global__ __launch_bounds__(256) void plate_kernel(
    const float* __restrict__ X,
    const float* __restrict__ thr_p,
    float* __restrict__ out_xyxy,
    float* __restrict__ out_keep,
    int ntiles)
{
    __shared__ float lds[5120];  // 1024 boxes * 5 floats = 20 KB

    const int tile = blockIdx.x;
    if (tile >= ntiles) return;
    const int j = threadIdx.x;
    const float thr = thr_p[0];

    // ---- coalesced global -> LDS (lanes adjacent, 16 B/lane) ----
    const f4* __restrict__ src = reinterpret_cast<const f4*>(X) + (size_t)tile * 1280;
    f4* __restrict__ ldsv = reinterpret_cast<f4*>(lds);
    #pragma unroll
    for (int k = 0; k < 5; ++k)
        ldsv[k * 256 + j] = src[k * 256 + j];

    __syncthreads();

    // ---- compute + coalesced stores ----
    f4*    __restrict__ dst = reinterpret_cast<f4*>(out_xyxy) + (size_t)tile * 1024;
    float* __restrict__ kp  = out_keep + (size_t)tile * 1024;

    #pragma unroll
    for (int k = 0; k < 4; ++k) {
        const int m = k * 256 + j;          // box index within tile
        const float x = lds[5 * m + 0];
        const float y = lds[5 * m + 1];
        const float w = lds[5 * m + 2];
        const float h = lds[5 * m + 3];
        const float s = lds[5 * m + 4];
        const bool keep = s > thr;
        const float hw = w * 0.5f;
        const float hh = h * 0.5f;
        f4 r;
        r.x = keep ? (x - hw) : 0.0f;
        r.y = keep ? (y - hh) : 0.0f;
        r.z = keep ? (x + hw) : 0.0f;
        r.w = keep ? (y + hh) : 0.0f;
        __builtin_nontemporal_store(r, &dst[m]);
        __builtin_nontemporal_store(keep ? 1.0f : 0.0f, &kp[m]);
    }
}

extern "C" void kernel_launch(void* const* d_in, const int* in_sizes, int n_in,
                              void* d_out, int out_size, void* d_ws, size_t ws_size,
                              hipStream_t stream)
{
    const float* X   = (const float*)d_in[0];
    const float* thr = (const float*)d_in[1];

    const long long n_boxes = (long long)in_sizes[0] / 5;   // 4,718,592
    const int ntiles = (int)(n_boxes / 1024);               // 4608 exactly

    float* out_xyxy = (float*)d_out;                        // N*4 floats
    float* out_keep = (float*)d_out + n_boxes * 4;          // N floats

    plate_kernel<<<ntiles, 256, 0, stream>>>(X, thr, out_xyxy, out_keep, ntiles);
}

// Round 3
// 32.728 us; speedup vs baseline: 1.0803x; 1.0007x over previous
//
#include <hip/hip_runtime.h>

// NumberPlateDetector: X (128,64,64,9,5) f32 -> boxes (N,5), N = 4,718,592
// out = concat flat: xyxy (N,4) f32, keep (N,) as 0/1 f32
//
// Memory-bound, 1:1 read:write. This version: async global_load_lds (16B)
// staging into a double-buffered LDS pair; each block owns 2 adjacent
// 1024-box tiles and stages tile k+1 while computing/storing tile k.
//   - block = 256 threads; tile = 1024 boxes = 5120 floats (20 KB);
//     2 buffers = 40 KB LDS -> 4 blocks/CU, 16 waves/CU (enough in-flight)
//   - global_load_lds: LDS dest is wave-uniform base + lane*16 (HW rule),
//     our staging layout is exactly linear -> legal
//   - compute: thread j handles boxes {j, 256+j, 512+j, 768+j}; LDS reads
//     at float-stride 5 (gcd(5,32)=1 -> only free 2-way lane aliasing)
//   - stores: coalesced float4 xyxy + scalar keep, non-temporal (outputs
//     never re-read -> preserve X's L3 residency across replays)

using f4 = __attribute__((ext_vector_type(4))) float;

typedef __attribute__((address_space(1))) const void gconst;
typedef __attribute__((address_space(3))) void svoid;

__global__ __launch_bounds__(256) void plate_kernel(
    const float* __restrict__ X,
    const float* __restrict__ thr_p,
    float* __restrict__ out_xyxy,
    float* __restrict__ out_keep)
{
    __shared__ float lds[2][5120];   // 2 x 20 KB

    const int b = blockIdx.x;
    const int j = threadIdx.x;
    const int wbase = j & ~63;       // wave-uniform lane base (lds dest rule)
    const float thr = thr_p[0];

    const int t0 = 2 * b;
    const int t1 = 2 * b + 1;

    // ---- async stage: tile -> lds[buf], 5 x global_load_lds(16B)/thread ----
    #define STAGE(buf, tile)                                                     \
        {                                                                        \
            const float* gsrc = X + (size_t)(tile) * 5120;                       \
            _Pragma("unroll")                                                    \
            for (int k = 0; k < 5; ++k) {                                        \
                __builtin_amdgcn_global_load_lds(                                \
                    (gconst*)(gsrc + 4 * (k * 256 + j)),                         \
                    (svoid*)&lds[buf][4 * (k * 256 + wbase)],                    \
                    16, 0, 0);                                                   \
            }                                                                    \
        }

    // ---- compute + coalesced non-temporal stores from lds[buf] ----
    #define COMPUTE(buf, tile)                                                   \
        {                                                                        \
            f4*    __restrict__ dst = reinterpret_cast<f4*>(out_xyxy)            \
                                      + (size_t)(tile) * 1024;                   \
            float* __restrict__ kp  = out_keep + (size_t)(tile) * 1024;          \
            _Pragma("unroll")                                                    \
            for (int k = 0; k < 4; ++k) {                                        \
                const int m = k * 256 + j;                                       \
                const float x = lds[buf][5 * m + 0];                             \
                const float y = lds[buf][5 * m + 1];                             \
                const float w = lds[buf][5 * m + 2];                             \
                const float h = lds[buf][5 * m + 3];                             \
                const float s = lds[buf][5 * m + 4];                             \
                const bool keep = s > thr;                                       \
                const float hw = w * 0.5f;                                       \
                const float hh = h * 0.5f;                                       \
                f4 r;                                                            \
                r.x = keep ? (x - hw) : 0.0f;                                    \
                r.y = keep ? (y - hh) : 0.0f;                                    \
                r.z = keep ? (x + hw) : 0.0f;                                    \
                r.w = keep ? (y + hh) : 0.0f;                                    \
                __builtin_nontemporal_store(r, &dst[m]);                         \
                __builtin_nontemporal_store(keep ? 1.0f : 0.0f, &kp[m]);         \
            }                                                                    \
        }

    STAGE(0, t0);
    __syncthreads();        // compiler drains vmcnt(0) before s_barrier -> buf0 ready
    STAGE(1, t1);           // in flight while we compute tile 0
    COMPUTE(0, t0);
    __syncthreads();        // drains vmcnt -> buf1 ready
    COMPUTE(1, t1);

    #undef STAGE
    #undef COMPUTE
}

extern "C" void kernel_launch(void* const* d_in, const int* in_sizes, int n_in,
                              void* d_out, int out_size, void* d_ws, size_t ws_size,
                              hipStream_t stream)
{
    const float* X   = (const float*)d_in[0];
    const float* thr = (const float*)d_in[1];

    const long long n_boxes = (long long)in_sizes[0] / 5;   // 4,718,592
    const int ntiles = (int)(n_boxes / 1024);               // 4608 exactly
    const int npairs = ntiles / 2;                          // 2304 blocks

    float* out_xyxy = (float*)d_out;                        // N*4 floats
    float* out_keep = (float*)d_out + n_boxes * 4;          // N floats

    plate_kernel<<<npairs, 256, 0, stream>>>(X, thr, out_xyxy, out_keep);
}